// Round 2
// baseline (833.580 us; speedup 1.0000x reference)
//
#include <hip/hip_runtime.h>

#define BN 8
#define NN 128
#define DN 768
#define EN 64
#define MLN 128
#define SN 64
#define HN 128
#define NHN 12

__device__ __forceinline__ float frelu(float x) { return x > 0.f ? x : 0.f; }

// ---------------------------------------------------------------------------
// K1: node projections. blockIdx.y selects one of 4 weight sets:
//   0: a  = node @ m_w1[0:768]        1: b = node @ m_w1[768:1536]
//   2: c  = node @ n_w1[128:896]      3: t = relu(node @ s_w1)
// 16 rows per block, K=768 in chunks of 64 staged transposed in LDS.
// ---------------------------------------------------------------------------
__global__ __launch_bounds__(256) void k1_proj(
    const float* __restrict__ node,
    const float* __restrict__ m_w1, const float* __restrict__ n_w1,
    const float* __restrict__ s_w1,
    float* __restrict__ pa, float* __restrict__ pb,
    float* __restrict__ pc, float* __restrict__ pt)
{
    __shared__ float XT[64][17];   // [k][row], 16 rows
    const int t = threadIdx.x;
    const int row0 = blockIdx.x * 16;

    const float* W; float* out; bool dorelu = false;
    switch (blockIdx.y) {
        case 0:  W = m_w1;                      out = pa; break;
        case 1:  W = m_w1 + (size_t)DN * HN;    out = pb; break;
        case 2:  W = n_w1 + (size_t)MLN * HN;   out = pc; break;
        default: W = s_w1;                      out = pt; dorelu = true; break;
    }

    const int rg = t & 7, cg = t >> 3;        // 8 row-groups x2 rows, 32 col-groups x4
    const int r0 = rg * 2, c0 = cg * 4;
    float acc[2][4] = {};

    const int srow = t >> 4, sc4 = t & 15;    // staging: 16 rows x 16 float4
    for (int kk = 0; kk < DN / 64; ++kk) {
        __syncthreads();
        float4 v = *reinterpret_cast<const float4*>(
            node + (size_t)(row0 + srow) * DN + kk * 64 + sc4 * 4);
        XT[sc4 * 4 + 0][srow] = v.x; XT[sc4 * 4 + 1][srow] = v.y;
        XT[sc4 * 4 + 2][srow] = v.z; XT[sc4 * 4 + 3][srow] = v.w;
        __syncthreads();
        #pragma unroll 8
        for (int k = 0; k < 64; ++k) {
            float4 w = *reinterpret_cast<const float4*>(W + (size_t)(kk * 64 + k) * HN + c0);
            float x0 = XT[k][r0], x1 = XT[k][r0 + 1];
            acc[0][0] += x0 * w.x; acc[0][1] += x0 * w.y;
            acc[0][2] += x0 * w.z; acc[0][3] += x0 * w.w;
            acc[1][0] += x1 * w.x; acc[1][1] += x1 * w.y;
            acc[1][2] += x1 * w.z; acc[1][3] += x1 * w.w;
        }
    }
    #pragma unroll
    for (int rr = 0; rr < 2; ++rr) {
        float4 o = make_float4(acc[rr][0], acc[rr][1], acc[rr][2], acc[rr][3]);
        if (dorelu) { o.x = frelu(o.x); o.y = frelu(o.y); o.z = frelu(o.z); o.w = frelu(o.w); }
        *reinterpret_cast<float4*>(out + (size_t)(row0 + r0 + rr) * HN + c0) = o;
    }
}

// ---------------------------------------------------------------------------
// K1b: shrink = t @ s_w2 (no relu on output); sa = shrink @ e_w1[0:64],
// sb = shrink @ e_w1[64:128].  32 rows per block.
// ---------------------------------------------------------------------------
__global__ __launch_bounds__(256) void k1b_shrink(
    const float* __restrict__ pt, const float* __restrict__ s_w2,
    const float* __restrict__ e_w1,
    float* __restrict__ psa, float* __restrict__ psb)
{
    __shared__ float TT[128][33];   // [k][row]
    __shared__ float SHT[64][33];   // [s][row]
    const int t = threadIdx.x;
    const int row0 = blockIdx.x * 32;

    #pragma unroll
    for (int it = 0; it < 4; ++it) {
        int idx = t + 256 * it;              // 0..1023
        int row = idx >> 5, c4 = idx & 31;
        float4 v = *reinterpret_cast<const float4*>(pt + (size_t)(row0 + row) * HN + c4 * 4);
        TT[c4 * 4 + 0][row] = v.x; TT[c4 * 4 + 1][row] = v.y;
        TT[c4 * 4 + 2][row] = v.z; TT[c4 * 4 + 3][row] = v.w;
    }
    __syncthreads();
    {   // shrink: 32x64, K=128
        const int rg = t & 7, cg = t >> 3;   // 8x4 rows, 32x2 cols
        const int r0 = rg * 4, c0 = cg * 2;
        float acc[4][2] = {};
        #pragma unroll 4
        for (int k = 0; k < HN; ++k) {
            float w0 = s_w2[k * SN + c0], w1 = s_w2[k * SN + c0 + 1];
            #pragma unroll
            for (int rr = 0; rr < 4; ++rr) {
                float x = TT[k][r0 + rr];
                acc[rr][0] += x * w0; acc[rr][1] += x * w1;
            }
        }
        #pragma unroll
        for (int rr = 0; rr < 4; ++rr) {
            SHT[c0][r0 + rr] = acc[rr][0];
            SHT[c0 + 1][r0 + rr] = acc[rr][1];
        }
    }
    __syncthreads();
    {   // sa|sb: 32x128 each, K=64
        const int rg = t & 7, cg = t >> 3;
        const int r0 = rg * 4, c0 = cg * 4;
        float aa[4][4] = {}; float ab[4][4] = {};
        #pragma unroll 4
        for (int k = 0; k < SN; ++k) {
            float4 wa = *reinterpret_cast<const float4*>(e_w1 + (size_t)k * HN + c0);
            float4 wb = *reinterpret_cast<const float4*>(e_w1 + (size_t)(SN + k) * HN + c0);
            #pragma unroll
            for (int rr = 0; rr < 4; ++rr) {
                float x = SHT[k][r0 + rr];
                aa[rr][0] += x * wa.x; aa[rr][1] += x * wa.y;
                aa[rr][2] += x * wa.z; aa[rr][3] += x * wa.w;
                ab[rr][0] += x * wb.x; ab[rr][1] += x * wb.y;
                ab[rr][2] += x * wb.z; ab[rr][3] += x * wb.w;
            }
        }
        #pragma unroll
        for (int rr = 0; rr < 4; ++rr) {
            *reinterpret_cast<float4*>(psa + (size_t)(row0 + r0 + rr) * HN + c0) =
                make_float4(aa[rr][0], aa[rr][1], aa[rr][2], aa[rr][3]);
            *reinterpret_cast<float4*>(psb + (size_t)(row0 + r0 + rr) * HN + c0) =
                make_float4(ab[rr][0], ab[rr][1], ab[rr][2], ab[rr][3]);
        }
    }
}

// ---------------------------------------------------------------------------
// K2: fused per-edge kernel. One block = 32 edges (b, i, j0..j0+31).
//   H1m = relu(edge@W1m + a_i + b_j);  H2m = relu(H1m@m_w2) -> column sums
//   H1e = relu(edge@W1e + sa_i + sb_j); H2e = relu(H1e@e_w2);
//   eo  = edge + (edge>0) * (H2e@e_w3)
//   FINAL: out = eo @ mask_w + mask_b  (layer-2 edge never written to HBM)
// ---------------------------------------------------------------------------
template <bool FINAL>
__global__ __launch_bounds__(256) void k2_edge(
    const float* __restrict__ edge_src,
    const float* __restrict__ pa, const float* __restrict__ pb,
    const float* __restrict__ psa, const float* __restrict__ psb,
    const float* __restrict__ m_w1, const float* __restrict__ m_w2,
    const float* __restrict__ e_w1, const float* __restrict__ e_w2,
    const float* __restrict__ e_w3,
    float* __restrict__ pcs,
    float* __restrict__ edge_dst,
    const float* __restrict__ maskw, const float* __restrict__ maskb,
    float* __restrict__ outE)
{
    __shared__ float XeT[64][37];   // [e][jj] transposed edge tile
    __shared__ float H1m[32][129];
    __shared__ float H1e[32][129];
    __shared__ float csP[8][132];
    __shared__ float MW[EN * NHN + NHN];

    const int t = threadIdx.x;
    const int blk = blockIdx.x;
    const int jc = blk & 3, i = (blk >> 2) & 127, b = blk >> 9;
    const int j0 = jc * 32;
    const int bi = b * NN + i;
    const float* w1m = m_w1 + (size_t)(2 * DN) * HN;
    const float* w1e = e_w1 + (size_t)(2 * SN) * HN;

    {   // stage 32x64 edge tile, transposed into LDS
        const float* ep = edge_src + ((size_t)bi * NN + j0) * EN;
        #pragma unroll
        for (int it = 0; it < 2; ++it) {
            int idx = t + 256 * it;          // 0..511
            int row = idx >> 4, c4 = idx & 15;
            float4 v = *reinterpret_cast<const float4*>(ep + row * EN + c4 * 4);
            XeT[c4 * 4 + 0][row] = v.x; XeT[c4 * 4 + 1][row] = v.y;
            XeT[c4 * 4 + 2][row] = v.z; XeT[c4 * 4 + 3][row] = v.w;
        }
    }
    if (FINAL) {
        for (int idx = t; idx < EN * NHN; idx += 256) MW[idx] = maskw[idx];
        if (t < NHN) MW[EN * NHN + t] = maskb[t];
    }
    __syncthreads();

    const int rg = t & 7, cg = t >> 3;        // 8x4 rows, 32x4 cols
    const int r0 = rg * 4, c0 = cg * 4;

    {   // GEMM1m + GEMM1e (K=64) from XeT
        float am[4][4] = {}; float ae[4][4] = {};
        #pragma unroll 4
        for (int k = 0; k < EN; ++k) {
            float4 wm = *reinterpret_cast<const float4*>(w1m + (size_t)k * HN + c0);
            float4 we = *reinterpret_cast<const float4*>(w1e + (size_t)k * HN + c0);
            float x[4];
            #pragma unroll
            for (int rr = 0; rr < 4; ++rr) x[rr] = XeT[k][r0 + rr];
            #pragma unroll
            for (int rr = 0; rr < 4; ++rr) {
                am[rr][0] += x[rr] * wm.x; am[rr][1] += x[rr] * wm.y;
                am[rr][2] += x[rr] * wm.z; am[rr][3] += x[rr] * wm.w;
                ae[rr][0] += x[rr] * we.x; ae[rr][1] += x[rr] * we.y;
                ae[rr][2] += x[rr] * we.z; ae[rr][3] += x[rr] * we.w;
            }
        }
        float4 av  = *reinterpret_cast<const float4*>(pa  + (size_t)bi * HN + c0);
        float4 sav = *reinterpret_cast<const float4*>(psa + (size_t)bi * HN + c0);
        float aarr[4]  = {av.x, av.y, av.z, av.w};
        float saarr[4] = {sav.x, sav.y, sav.z, sav.w};
        #pragma unroll
        for (int rr = 0; rr < 4; ++rr) {
            int gj = b * NN + j0 + r0 + rr;
            float4 bv  = *reinterpret_cast<const float4*>(pb  + (size_t)gj * HN + c0);
            float4 sbv = *reinterpret_cast<const float4*>(psb + (size_t)gj * HN + c0);
            float barr[4]  = {bv.x, bv.y, bv.z, bv.w};
            float sbarr[4] = {sbv.x, sbv.y, sbv.z, sbv.w};
            #pragma unroll
            for (int cc = 0; cc < 4; ++cc) {
                H1m[r0 + rr][c0 + cc] = frelu(am[rr][cc] + aarr[cc] + barr[cc]);
                H1e[r0 + rr][c0 + cc] = frelu(ae[rr][cc] + saarr[cc] + sbarr[cc]);
            }
        }
    }
    __syncthreads();

    {   // GEMM2m: relu(H1m @ m_w2) with fused column sums (H2m never stored)
        float acc[4][4] = {};
        #pragma unroll 4
        for (int k = 0; k < HN; ++k) {
            float4 w = *reinterpret_cast<const float4*>(m_w2 + (size_t)k * HN + c0);
            #pragma unroll
            for (int rr = 0; rr < 4; ++rr) {
                float x = H1m[r0 + rr][k];
                acc[rr][0] += x * w.x; acc[rr][1] += x * w.y;
                acc[rr][2] += x * w.z; acc[rr][3] += x * w.w;
            }
        }
        #pragma unroll
        for (int cc = 0; cc < 4; ++cc) {
            csP[rg][c0 + cc] = frelu(acc[0][cc]) + frelu(acc[1][cc]) +
                               frelu(acc[2][cc]) + frelu(acc[3][cc]);
        }
    }
    __syncthreads();

    if (t < HN) {   // column-sum reduce -> message partials
        float s = 0.f;
        #pragma unroll
        for (int g = 0; g < 8; ++g) s += csP[g][t];
        pcs[((size_t)jc * BN * NN + bi) * HN + t] = s;
    }
    {   // GEMM2e: H2e = relu(H1e @ e_w2) -> stored into H1m buffer
        float acc[4][4] = {};
        #pragma unroll 4
        for (int k = 0; k < HN; ++k) {
            float4 w = *reinterpret_cast<const float4*>(e_w2 + (size_t)k * HN + c0);
            #pragma unroll
            for (int rr = 0; rr < 4; ++rr) {
                float x = H1e[r0 + rr][k];
                acc[rr][0] += x * w.x; acc[rr][1] += x * w.y;
                acc[rr][2] += x * w.z; acc[rr][3] += x * w.w;
            }
        }
        #pragma unroll
        for (int rr = 0; rr < 4; ++rr)
            #pragma unroll
            for (int cc = 0; cc < 4; ++cc)
                H1m[r0 + rr][c0 + cc] = frelu(acc[rr][cc]);
    }
    __syncthreads();

    {   // GEMM3e: Eout = H2e @ e_w3 (32x64, K=128), residual + mask
        const int r2 = (t & 15) * 2, c2 = (t >> 4) * 4;
        float acc[2][4] = {};
        #pragma unroll 4
        for (int k = 0; k < HN; ++k) {
            float4 w = *reinterpret_cast<const float4*>(e_w3 + (size_t)k * EN + c2);
            float x0 = H1m[r2][k], x1 = H1m[r2 + 1][k];
            acc[0][0] += x0 * w.x; acc[0][1] += x0 * w.y;
            acc[0][2] += x0 * w.z; acc[0][3] += x0 * w.w;
            acc[1][0] += x1 * w.x; acc[1][1] += x1 * w.y;
            acc[1][2] += x1 * w.z; acc[1][3] += x1 * w.w;
        }
        float* EO = &H1e[0][0];   // reuse as [32][65]
        #pragma unroll
        for (int rr = 0; rr < 2; ++rr) {
            float e0 = XeT[c2 + 0][r2 + rr], e1 = XeT[c2 + 1][r2 + rr];
            float e2 = XeT[c2 + 2][r2 + rr], e3 = XeT[c2 + 3][r2 + rr];
            float4 o;
            o.x = e0 + (e0 > 0.f ? acc[rr][0] : 0.f);
            o.y = e1 + (e1 > 0.f ? acc[rr][1] : 0.f);
            o.z = e2 + (e2 > 0.f ? acc[rr][2] : 0.f);
            o.w = e3 + (e3 > 0.f ? acc[rr][3] : 0.f);
            if (!FINAL) {
                *reinterpret_cast<float4*>(
                    edge_dst + ((size_t)bi * NN + j0 + r2 + rr) * EN + c2) = o;
            } else {
                EO[(r2 + rr) * 65 + c2 + 0] = o.x;
                EO[(r2 + rr) * 65 + c2 + 1] = o.y;
                EO[(r2 + rr) * 65 + c2 + 2] = o.z;
                EO[(r2 + rr) * 65 + c2 + 3] = o.w;
            }
        }
    }
    if (FINAL) {
        __syncthreads();
        const float* EO = &H1e[0][0];
        if (t < 128) {
            int row = t & 31, g = t >> 5;   // 4 groups x 3 output cols
            float o0 = MW[EN * NHN + 3 * g + 0];
            float o1 = MW[EN * NHN + 3 * g + 1];
            float o2 = MW[EN * NHN + 3 * g + 2];
            #pragma unroll 4
            for (int e = 0; e < EN; ++e) {
                float x = EO[row * 65 + e];
                o0 += x * MW[e * NHN + 3 * g + 0];
                o1 += x * MW[e * NHN + 3 * g + 1];
                o2 += x * MW[e * NHN + 3 * g + 2];
            }
            float* op = outE + ((size_t)bi * NN + j0 + row) * NHN + 3 * g;
            op[0] = o0; op[1] = o1; op[2] = o2;
        }
    }
}

// ---------------------------------------------------------------------------
// K3a: message = (sum_jc cs)/128; MSG = message@m_w3;
//      P = relu(MSG@n_w1[:128] + c); Q = relu(P@n_w2) -> pq
// ---------------------------------------------------------------------------
__global__ __launch_bounds__(256) void k3a(
    const float* __restrict__ pcs, const float* __restrict__ pc,
    const float* __restrict__ m_w3, const float* __restrict__ n_w1,
    const float* __restrict__ n_w2, float* __restrict__ pq)
{
    __shared__ float bufA[32][129];
    __shared__ float bufB[32][129];
    const int t = threadIdx.x;
    const int row0 = blockIdx.x * 32;
    const size_t CH = (size_t)BN * NN * HN;

    #pragma unroll
    for (int it = 0; it < 4; ++it) {
        int idx = t + 256 * it;
        int row = idx >> 5, c4 = idx & 31;
        size_t base = (size_t)(row0 + row) * HN + c4 * 4;
        float4 v0 = *reinterpret_cast<const float4*>(pcs + base);
        float4 v1 = *reinterpret_cast<const float4*>(pcs + CH + base);
        float4 v2 = *reinterpret_cast<const float4*>(pcs + 2 * CH + base);
        float4 v3 = *reinterpret_cast<const float4*>(pcs + 3 * CH + base);
        bufA[row][c4 * 4 + 0] = (v0.x + v1.x + v2.x + v3.x) * (1.f / 128.f);
        bufA[row][c4 * 4 + 1] = (v0.y + v1.y + v2.y + v3.y) * (1.f / 128.f);
        bufA[row][c4 * 4 + 2] = (v0.z + v1.z + v2.z + v3.z) * (1.f / 128.f);
        bufA[row][c4 * 4 + 3] = (v0.w + v1.w + v2.w + v3.w) * (1.f / 128.f);
    }
    __syncthreads();
    const int rg = t & 7, cg = t >> 3;
    const int r0 = rg * 4, c0 = cg * 4;
    {   // A: MSG = bufA @ m_w3 (no relu)
        float acc[4][4] = {};
        #pragma unroll 4
        for (int k = 0; k < HN; ++k) {
            float4 w = *reinterpret_cast<const float4*>(m_w3 + (size_t)k * HN + c0);
            #pragma unroll
            for (int rr = 0; rr < 4; ++rr) {
                float x = bufA[r0 + rr][k];
                acc[rr][0] += x * w.x; acc[rr][1] += x * w.y;
                acc[rr][2] += x * w.z; acc[rr][3] += x * w.w;
            }
        }
        #pragma unroll
        for (int rr = 0; rr < 4; ++rr)
            #pragma unroll
            for (int cc = 0; cc < 4; ++cc) bufB[r0 + rr][c0 + cc] = acc[rr][cc];
    }
    __syncthreads();
    {   // B: P = relu(MSG @ n_w1[:128] + c)
        float acc[4][4] = {};
        #pragma unroll 4
        for (int k = 0; k < HN; ++k) {
            float4 w = *reinterpret_cast<const float4*>(n_w1 + (size_t)k * HN + c0);
            #pragma unroll
            for (int rr = 0; rr < 4; ++rr) {
                float x = bufB[r0 + rr][k];
                acc[rr][0] += x * w.x; acc[rr][1] += x * w.y;
                acc[rr][2] += x * w.z; acc[rr][3] += x * w.w;
            }
        }
        #pragma unroll
        for (int rr = 0; rr < 4; ++rr) {
            float4 cv = *reinterpret_cast<const float4*>(
                pc + (size_t)(row0 + r0 + rr) * HN + c0);
            bufA[r0 + rr][c0 + 0] = frelu(acc[rr][0] + cv.x);
            bufA[r0 + rr][c0 + 1] = frelu(acc[rr][1] + cv.y);
            bufA[r0 + rr][c0 + 2] = frelu(acc[rr][2] + cv.z);
            bufA[r0 + rr][c0 + 3] = frelu(acc[rr][3] + cv.w);
        }
    }
    __syncthreads();
    {   // C: Q = relu(P @ n_w2) -> global pq
        float acc[4][4] = {};
        #pragma unroll 4
        for (int k = 0; k < HN; ++k) {
            float4 w = *reinterpret_cast<const float4*>(n_w2 + (size_t)k * HN + c0);
            #pragma unroll
            for (int rr = 0; rr < 4; ++rr) {
                float x = bufA[r0 + rr][k];
                acc[rr][0] += x * w.x; acc[rr][1] += x * w.y;
                acc[rr][2] += x * w.z; acc[rr][3] += x * w.w;
            }
        }
        #pragma unroll
        for (int rr = 0; rr < 4; ++rr)
            *reinterpret_cast<float4*>(pq + (size_t)(row0 + r0 + rr) * HN + c0) =
                make_float4(frelu(acc[rr][0]), frelu(acc[rr][1]),
                            frelu(acc[rr][2]), frelu(acc[rr][3]));
    }
}

// ---------------------------------------------------------------------------
// K3b: node_out = node + Q @ n_w3   (1024x768, K=128; 32 rows x 128-col chunk)
// ---------------------------------------------------------------------------
__global__ __launch_bounds__(256) void k3b(
    const float* __restrict__ pq, const float* __restrict__ n_w3,
    const float* __restrict__ node_src, float* __restrict__ node_dst)
{
    __shared__ float QT[32][129];
    const int t = threadIdx.x;
    const int row0 = blockIdx.x * 32;
    const int cc0 = blockIdx.y * 128;

    #pragma unroll
    for (int it = 0; it < 4; ++it) {
        int idx = t + 256 * it;
        int row = idx >> 5, c4 = idx & 31;
        float4 v = *reinterpret_cast<const float4*>(pq + (size_t)(row0 + row) * HN + c4 * 4);
        QT[row][c4 * 4 + 0] = v.x; QT[row][c4 * 4 + 1] = v.y;
        QT[row][c4 * 4 + 2] = v.z; QT[row][c4 * 4 + 3] = v.w;
    }
    __syncthreads();
    const int rg = t & 7, cg = t >> 3;
    const int r0 = rg * 4, c0 = cg * 4;
    float acc[4][4] = {};
    #pragma unroll 4
    for (int k = 0; k < HN; ++k) {
        float4 w = *reinterpret_cast<const float4*>(n_w3 + (size_t)k * DN + cc0 + c0);
        #pragma unroll
        for (int rr = 0; rr < 4; ++rr) {
            float x = QT[r0 + rr][k];
            acc[rr][0] += x * w.x; acc[rr][1] += x * w.y;
            acc[rr][2] += x * w.z; acc[rr][3] += x * w.w;
        }
    }
    #pragma unroll
    for (int rr = 0; rr < 4; ++rr) {
        size_t off = (size_t)(row0 + r0 + rr) * DN + cc0 + c0;
        float4 nv = *reinterpret_cast<const float4*>(node_src + off);
        *reinterpret_cast<float4*>(node_dst + off) =
            make_float4(nv.x + acc[rr][0], nv.y + acc[rr][1],
                        nv.z + acc[rr][2], nv.w + acc[rr][3]);
    }
}

// ---------------------------------------------------------------------------
extern "C" void kernel_launch(void* const* d_in, const int* in_sizes, int n_in,
                              void* d_out, int out_size, void* d_ws, size_t ws_size,
                              hipStream_t stream)
{
    const float* nodeIn = (const float*)d_in[0];
    const float* edgeIn = (const float*)d_in[1];
    const float* s_w1 = (const float*)d_in[3];
    const float* s_w2 = (const float*)d_in[4];
    const float* m_w1 = (const float*)d_in[5];
    const float* m_w2 = (const float*)d_in[6];
    const float* m_w3 = (const float*)d_in[7];
    const float* n_w1 = (const float*)d_in[8];
    const float* n_w2 = (const float*)d_in[9];
    const float* n_w3 = (const float*)d_in[10];
    const float* e_w1 = (const float*)d_in[11];
    const float* e_w2 = (const float*)d_in[12];
    const float* e_w3 = (const float*)d_in[13];
    const float* maskw = (const float*)d_in[14];
    const float* maskb = (const float*)d_in[15];

    float* outN = (float*)d_out;
    float* outE = outN + (size_t)BN * NN * DN;

    const size_t edgeFl = (size_t)BN * NN * NN * EN;   // 8388608
    const size_t nodeFl = (size_t)BN * NN * DN;        // 786432
    const size_t rowFl  = (size_t)BN * NN * HN;        // 131072

    float* w = (float*)d_ws;
    const size_t needBig = edgeFl + nodeFl + 10 * rowFl;
    float *edge1, *node1;
    if (ws_size >= needBig * sizeof(float)) {
        edge1 = w; w += edgeFl;
        node1 = w; w += nodeFl;
    } else {
        // in-place fallback: harness restores inputs before every timed launch
        edge1 = (float*)d_in[1];
        node1 = (float*)d_in[0];
    }
    float* pa  = w; w += rowFl;
    float* pb  = w; w += rowFl;
    float* pc  = w; w += rowFl;
    float* pt  = w; w += rowFl;
    float* psa = w; w += rowFl;
    float* psb = w; w += rowFl;
    float* pcs = w; w += 4 * rowFl;
    float* pq  = pt;   // pt is dead after k1b; reuse for Q

    for (int l = 0; l < 2; ++l) {
        const float* nsrc = l ? (const float*)node1 : nodeIn;
        const float* esrc = l ? (const float*)edge1 : edgeIn;
        float* ndst = l ? outN : node1;

        k1_proj<<<dim3(64, 4), 256, 0, stream>>>(nsrc, m_w1, n_w1, s_w1, pa, pb, pc, pt);
        k1b_shrink<<<dim3(32), 256, 0, stream>>>(pt, s_w2, e_w1, psa, psb);
        if (l == 0)
            k2_edge<false><<<dim3(4096), 256, 0, stream>>>(
                esrc, pa, pb, psa, psb, m_w1, m_w2, e_w1, e_w2, e_w3,
                pcs, edge1, maskw, maskb, outE);
        else
            k2_edge<true><<<dim3(4096), 256, 0, stream>>>(
                esrc, pa, pb, psa, psb, m_w1, m_w2, e_w1, e_w2, e_w3,
                pcs, nullptr, maskw, maskb, outE);
        k3a<<<dim3(32), 256, 0, stream>>>(pcs, pc, m_w3, n_w1, n_w2, pq);
        k3b<<<dim3(32, 6), 256, 0, stream>>>(pq, n_w3, nsrc, ndst);
    }
}

// Round 3
// 443.644 us; speedup vs baseline: 1.8789x; 1.8789x over previous
//
#include <hip/hip_runtime.h>

#define BN 8
#define NN 128
#define DN 768
#define EN 64
#define MLN 128
#define SN 64
#define HN 128
#define NHN 12

typedef __attribute__((ext_vector_type(8))) short short8;   // 8 bf16 (4 VGPR)
typedef __attribute__((ext_vector_type(4))) float f32x4;    // MFMA C/D

#define MFMA16(a, b, c) __builtin_amdgcn_mfma_f32_16x16x32_bf16(a, b, c, 0, 0, 0)

__device__ __forceinline__ float frelu(float x) { return x > 0.f ? x : 0.f; }

__device__ __forceinline__ unsigned short f2bf(float x) {
    unsigned u = __builtin_bit_cast(unsigned, x);
    u = (u + 0x7fffu + ((u >> 16) & 1u)) >> 16;     // RNE
    return (unsigned short)u;
}

// ---------------------------------------------------------------------------
// kprep: convert the 5 edge-path weights to bf16, transposed to [N][K]
// (MFMA B-operand layout). Regions in wb (ushort):
//   [0,8192)      w1m_b [128][64]   <- m_w1 rows [1536,1600)
//   [8192,16384)  w1e_b [128][64]   <- e_w1 rows [128,192)
//   [16384,32768) w2m_b [128][128]  <- m_w2^T
//   [32768,49152) w2e_b [128][128]  <- e_w2^T
//   [49152,57344) w3e_b [64][128]   <- e_w3^T
// ---------------------------------------------------------------------------
__global__ __launch_bounds__(256) void kprep(
    const float* __restrict__ m_w1, const float* __restrict__ e_w1,
    const float* __restrict__ m_w2, const float* __restrict__ e_w2,
    const float* __restrict__ e_w3, unsigned short* __restrict__ wb)
{
    int idx = blockIdx.x * 256 + threadIdx.x;   // 0..57343
    float v;
    if (idx < 8192) {
        int n = idx >> 6, k = idx & 63;
        v = m_w1[(size_t)(2 * DN + k) * HN + n];
    } else if (idx < 16384) {
        int r = idx - 8192; int n = r >> 6, k = r & 63;
        v = e_w1[(size_t)(2 * SN + k) * HN + n];
    } else if (idx < 32768) {
        int r = idx - 16384; int n = r >> 7, k = r & 127;
        v = m_w2[(size_t)k * HN + n];
    } else if (idx < 49152) {
        int r = idx - 32768; int n = r >> 7, k = r & 127;
        v = e_w2[(size_t)k * HN + n];
    } else {
        int r = idx - 49152; int n = r >> 7, k = r & 127;
        v = e_w3[(size_t)k * EN + n];
    }
    wb[idx] = f2bf(v);
}

// ---------------------------------------------------------------------------
// K1: node projections (fp32, unchanged). blockIdx.y selects weight set.
// ---------------------------------------------------------------------------
__global__ __launch_bounds__(256) void k1_proj(
    const float* __restrict__ node,
    const float* __restrict__ m_w1, const float* __restrict__ n_w1,
    const float* __restrict__ s_w1,
    float* __restrict__ pa, float* __restrict__ pb,
    float* __restrict__ pc, float* __restrict__ pt)
{
    __shared__ float XT[64][17];
    const int t = threadIdx.x;
    const int row0 = blockIdx.x * 16;

    const float* W; float* out; bool dorelu = false;
    switch (blockIdx.y) {
        case 0:  W = m_w1;                      out = pa; break;
        case 1:  W = m_w1 + (size_t)DN * HN;    out = pb; break;
        case 2:  W = n_w1 + (size_t)MLN * HN;   out = pc; break;
        default: W = s_w1;                      out = pt; dorelu = true; break;
    }

    const int rg = t & 7, cg = t >> 3;
    const int r0 = rg * 2, c0 = cg * 4;
    float acc[2][4] = {};

    const int srow = t >> 4, sc4 = t & 15;
    for (int kk = 0; kk < DN / 64; ++kk) {
        __syncthreads();
        float4 v = *reinterpret_cast<const float4*>(
            node + (size_t)(row0 + srow) * DN + kk * 64 + sc4 * 4);
        XT[sc4 * 4 + 0][srow] = v.x; XT[sc4 * 4 + 1][srow] = v.y;
        XT[sc4 * 4 + 2][srow] = v.z; XT[sc4 * 4 + 3][srow] = v.w;
        __syncthreads();
        #pragma unroll 8
        for (int k = 0; k < 64; ++k) {
            float4 w = *reinterpret_cast<const float4*>(W + (size_t)(kk * 64 + k) * HN + c0);
            float x0 = XT[k][r0], x1 = XT[k][r0 + 1];
            acc[0][0] += x0 * w.x; acc[0][1] += x0 * w.y;
            acc[0][2] += x0 * w.z; acc[0][3] += x0 * w.w;
            acc[1][0] += x1 * w.x; acc[1][1] += x1 * w.y;
            acc[1][2] += x1 * w.z; acc[1][3] += x1 * w.w;
        }
    }
    #pragma unroll
    for (int rr = 0; rr < 2; ++rr) {
        float4 o = make_float4(acc[rr][0], acc[rr][1], acc[rr][2], acc[rr][3]);
        if (dorelu) { o.x = frelu(o.x); o.y = frelu(o.y); o.z = frelu(o.z); o.w = frelu(o.w); }
        *reinterpret_cast<float4*>(out + (size_t)(row0 + r0 + rr) * HN + c0) = o;
    }
}

// ---------------------------------------------------------------------------
// K1b: shrink + sa/sb projections (fp32, unchanged).
// ---------------------------------------------------------------------------
__global__ __launch_bounds__(256) void k1b_shrink(
    const float* __restrict__ pt, const float* __restrict__ s_w2,
    const float* __restrict__ e_w1,
    float* __restrict__ psa, float* __restrict__ psb)
{
    __shared__ float TT[128][33];
    __shared__ float SHT[64][33];
    const int t = threadIdx.x;
    const int row0 = blockIdx.x * 32;

    #pragma unroll
    for (int it = 0; it < 4; ++it) {
        int idx = t + 256 * it;
        int row = idx >> 5, c4 = idx & 31;
        float4 v = *reinterpret_cast<const float4*>(pt + (size_t)(row0 + row) * HN + c4 * 4);
        TT[c4 * 4 + 0][row] = v.x; TT[c4 * 4 + 1][row] = v.y;
        TT[c4 * 4 + 2][row] = v.z; TT[c4 * 4 + 3][row] = v.w;
    }
    __syncthreads();
    {
        const int rg = t & 7, cg = t >> 3;
        const int r0 = rg * 4, c0 = cg * 2;
        float acc[4][2] = {};
        #pragma unroll 4
        for (int k = 0; k < HN; ++k) {
            float w0 = s_w2[k * SN + c0], w1 = s_w2[k * SN + c0 + 1];
            #pragma unroll
            for (int rr = 0; rr < 4; ++rr) {
                float x = TT[k][r0 + rr];
                acc[rr][0] += x * w0; acc[rr][1] += x * w1;
            }
        }
        #pragma unroll
        for (int rr = 0; rr < 4; ++rr) {
            SHT[c0][r0 + rr] = acc[rr][0];
            SHT[c0 + 1][r0 + rr] = acc[rr][1];
        }
    }
    __syncthreads();
    {
        const int rg = t & 7, cg = t >> 3;
        const int r0 = rg * 4, c0 = cg * 4;
        float aa[4][4] = {}; float ab[4][4] = {};
        #pragma unroll 4
        for (int k = 0; k < SN; ++k) {
            float4 wa = *reinterpret_cast<const float4*>(e_w1 + (size_t)k * HN + c0);
            float4 wb2 = *reinterpret_cast<const float4*>(e_w1 + (size_t)(SN + k) * HN + c0);
            #pragma unroll
            for (int rr = 0; rr < 4; ++rr) {
                float x = SHT[k][r0 + rr];
                aa[rr][0] += x * wa.x; aa[rr][1] += x * wa.y;
                aa[rr][2] += x * wa.z; aa[rr][3] += x * wa.w;
                ab[rr][0] += x * wb2.x; ab[rr][1] += x * wb2.y;
                ab[rr][2] += x * wb2.z; ab[rr][3] += x * wb2.w;
            }
        }
        #pragma unroll
        for (int rr = 0; rr < 4; ++rr) {
            *reinterpret_cast<float4*>(psa + (size_t)(row0 + r0 + rr) * HN + c0) =
                make_float4(aa[rr][0], aa[rr][1], aa[rr][2], aa[rr][3]);
            *reinterpret_cast<float4*>(psb + (size_t)(row0 + r0 + rr) * HN + c0) =
                make_float4(ab[rr][0], ab[rr][1], ab[rr][2], ab[rr][3]);
        }
    }
}

// ---------------------------------------------------------------------------
// K2 (MFMA): fused per-edge kernel, bf16 matrix cores, fp32 bias/relu/residual.
// Block = 32 edges (b,i,j0..j0+31); 4 waves; wave w owns output cols w*32..w*32+31.
// Fragment conventions (gfx950 16x16x32 bf16, m89-verified):
//   A (left, MxK row-major): lane&15 = m-row, k = (lane>>4)*8 + i
//   B (right, [N][K] N-major): lane&15 = n-col, k = (lane>>4)*8 + i
//   D: col = lane&15, row = (lane>>4)*4 + reg
// ---------------------------------------------------------------------------
template <bool FINAL>
__global__ __launch_bounds__(256, 4) void k2_mfma(
    const float* __restrict__ edge_src,
    const float* __restrict__ pa, const float* __restrict__ pb,
    const float* __restrict__ psa, const float* __restrict__ psb,
    const unsigned short* __restrict__ wb,
    float* __restrict__ pcs, float* __restrict__ edge_dst,
    const float* __restrict__ maskw, const float* __restrict__ maskb,
    float* __restrict__ outE)
{
    __shared__ float          Ef[32][68];    // fp32 edge tile (residual/mask, exact)
    __shared__ unsigned short Eb[32][72];    // bf16 edge tile (A-operand), 2-way banks
    __shared__ unsigned short Ab[32][136];   // H1m, later H2e
    __shared__ unsigned short Bb[32][136];   // H1e
    __shared__ float          MW[EN * NHN + NHN];

    const int t = threadIdx.x;
    const int wid = t >> 6, lane = t & 63;
    const int lrow = lane & 15, ks = lane >> 4;
    const int blk = blockIdx.x;
    const int jc = blk & 3, i = (blk >> 2) & 127, b = blk >> 9;
    const int j0 = jc * 32, bi = b * NN + i;
    const int wn0 = wid * 32;

    const unsigned short* w1m_b = wb;
    const unsigned short* w1e_b = wb + 8192;
    const unsigned short* w2m_b = wb + 16384;
    const unsigned short* w2e_b = wb + 32768;
    const unsigned short* w3e_b = wb + 49152;

    {   // stage edge tile: fp32 + bf16
        const float* ep = edge_src + ((size_t)bi * NN + j0) * EN;
        #pragma unroll
        for (int it = 0; it < 2; ++it) {
            int idx = t + 256 * it;
            int r = idx >> 4, c4 = (idx & 15) * 4;
            float4 v = *reinterpret_cast<const float4*>(ep + r * EN + c4);
            *reinterpret_cast<float4*>(&Ef[r][c4]) = v;
            ushort4 u;
            u.x = f2bf(v.x); u.y = f2bf(v.y); u.z = f2bf(v.z); u.w = f2bf(v.w);
            *reinterpret_cast<ushort4*>(&Eb[r][c4]) = u;
        }
    }
    if (FINAL) {
        for (int idx = t; idx < EN * NHN; idx += 256) MW[idx] = maskw[idx];
        if (t < NHN) MW[EN * NHN + t] = maskb[t];
    }
    __syncthreads();

    const f32x4 zf = {0.f, 0.f, 0.f, 0.f};

    // ---- G1m + G1e: E(32x64) @ W1{m,e}(64x128), bias, relu, -> bf16 LDS ----
    {
        f32x4 am[2][2], ae[2][2];
        #pragma unroll
        for (int mt = 0; mt < 2; ++mt)
            #pragma unroll
            for (int nt = 0; nt < 2; ++nt) { am[mt][nt] = zf; ae[mt][nt] = zf; }

        #pragma unroll
        for (int kk = 0; kk < 2; ++kk) {
            short8 a0 = *reinterpret_cast<const short8*>(&Eb[lrow][kk * 32 + ks * 8]);
            short8 a1 = *reinterpret_cast<const short8*>(&Eb[16 + lrow][kk * 32 + ks * 8]);
            #pragma unroll
            for (int nt = 0; nt < 2; ++nt) {
                const int n = wn0 + nt * 16 + lrow;
                short8 bm = *reinterpret_cast<const short8*>(w1m_b + n * 64 + kk * 32 + ks * 8);
                short8 be = *reinterpret_cast<const short8*>(w1e_b + n * 64 + kk * 32 + ks * 8);
                am[0][nt] = MFMA16(a0, bm, am[0][nt]);
                am[1][nt] = MFMA16(a1, bm, am[1][nt]);
                ae[0][nt] = MFMA16(a0, be, ae[0][nt]);
                ae[1][nt] = MFMA16(a1, be, ae[1][nt]);
            }
        }
        #pragma unroll
        for (int nt = 0; nt < 2; ++nt) {
            const int col = wn0 + nt * 16 + lrow;
            const float av  = pa[(size_t)bi * HN + col];
            const float sav = psa[(size_t)bi * HN + col];
            #pragma unroll
            for (int mt = 0; mt < 2; ++mt) {
                #pragma unroll
                for (int reg = 0; reg < 4; ++reg) {
                    const int row = mt * 16 + ks * 4 + reg;
                    const int gj = b * NN + j0 + row;
                    const float bv  = pb[(size_t)gj * HN + col];
                    const float sbv = psb[(size_t)gj * HN + col];
                    Ab[row][col] = f2bf(frelu(am[mt][nt][reg] + av + bv));
                    Bb[row][col] = f2bf(frelu(ae[mt][nt][reg] + sav + sbv));
                }
            }
        }
    }
    __syncthreads();

    // ---- G2m: relu(H1m @ m_w2), fused column sums -> pcs ----
    {
        f32x4 acc[2][2];
        #pragma unroll
        for (int mt = 0; mt < 2; ++mt)
            #pragma unroll
            for (int nt = 0; nt < 2; ++nt) acc[mt][nt] = zf;
        #pragma unroll
        for (int kk = 0; kk < 4; ++kk) {
            short8 a0 = *reinterpret_cast<const short8*>(&Ab[lrow][kk * 32 + ks * 8]);
            short8 a1 = *reinterpret_cast<const short8*>(&Ab[16 + lrow][kk * 32 + ks * 8]);
            #pragma unroll
            for (int nt = 0; nt < 2; ++nt) {
                const int n = wn0 + nt * 16 + lrow;
                short8 bm = *reinterpret_cast<const short8*>(w2m_b + n * 128 + kk * 32 + ks * 8);
                acc[0][nt] = MFMA16(a0, bm, acc[0][nt]);
                acc[1][nt] = MFMA16(a1, bm, acc[1][nt]);
            }
        }
        #pragma unroll
        for (int nt = 0; nt < 2; ++nt) {
            float s = 0.f;
            #pragma unroll
            for (int mt = 0; mt < 2; ++mt)
                #pragma unroll
                for (int reg = 0; reg < 4; ++reg) s += frelu(acc[mt][nt][reg]);
            s += __shfl_xor(s, 16);
            s += __shfl_xor(s, 32);
            if (ks == nt)
                pcs[((size_t)jc * BN * NN + bi) * HN + wn0 + nt * 16 + lrow] = s;
        }
    }

    // ---- G2e: H2e = relu(H1e @ e_w2) (kept in regs until Ab is free) ----
    f32x4 h2[2][2];
    {
        #pragma unroll
        for (int mt = 0; mt < 2; ++mt)
            #pragma unroll
            for (int nt = 0; nt < 2; ++nt) h2[mt][nt] = zf;
        #pragma unroll
        for (int kk = 0; kk < 4; ++kk) {
            short8 a0 = *reinterpret_cast<const short8*>(&Bb[lrow][kk * 32 + ks * 8]);
            short8 a1 = *reinterpret_cast<const short8*>(&Bb[16 + lrow][kk * 32 + ks * 8]);
            #pragma unroll
            for (int nt = 0; nt < 2; ++nt) {
                const int n = wn0 + nt * 16 + lrow;
                short8 be = *reinterpret_cast<const short8*>(w2e_b + n * 128 + kk * 32 + ks * 8);
                h2[0][nt] = MFMA16(a0, be, h2[0][nt]);
                h2[1][nt] = MFMA16(a1, be, h2[1][nt]);
            }
        }
    }
    __syncthreads();   // all waves done reading Ab (H1m)

    #pragma unroll
    for (int nt = 0; nt < 2; ++nt) {
        const int col = wn0 + nt * 16 + lrow;
        #pragma unroll
        for (int mt = 0; mt < 2; ++mt)
            #pragma unroll
            for (int reg = 0; reg < 4; ++reg)
                Ab[mt * 16 + ks * 4 + reg][col] = f2bf(frelu(h2[mt][nt][reg]));
    }
    __syncthreads();

    // ---- G3e: Eout = H2e @ e_w3 (32x64, K=128) + residual + (edge>0) mask ----
    {
        f32x4 acc3[2]; acc3[0] = zf; acc3[1] = zf;
        const int n0 = wid * 16;
        #pragma unroll
        for (int kk = 0; kk < 4; ++kk) {
            short8 a0 = *reinterpret_cast<const short8*>(&Ab[lrow][kk * 32 + ks * 8]);
            short8 a1 = *reinterpret_cast<const short8*>(&Ab[16 + lrow][kk * 32 + ks * 8]);
            short8 bw = *reinterpret_cast<const short8*>(w3e_b + (n0 + lrow) * 128 + kk * 32 + ks * 8);
            acc3[0] = MFMA16(a0, bw, acc3[0]);
            acc3[1] = MFMA16(a1, bw, acc3[1]);
        }
        #pragma unroll
        for (int mt = 0; mt < 2; ++mt) {
            #pragma unroll
            for (int reg = 0; reg < 4; ++reg) {
                const int row = mt * 16 + ks * 4 + reg;
                const int colc = n0 + lrow;           // 0..63
                const float ev = Ef[row][colc];
                const float o = ev + (ev > 0.f ? acc3[mt][reg] : 0.f);
                if (!FINAL)
                    edge_dst[((size_t)bi * NN + j0 + row) * EN + colc] = o;
                else
                    Ef[row][colc] = o;                // in-place (same lane r/w)
            }
        }
    }

    if (FINAL) {
        __syncthreads();
        if (t < 128) {   // masked projection: out = EO @ mask_w + mask_b
            int row = t & 31, g = t >> 5;             // 4 groups x 3 output cols
            float o0 = MW[EN * NHN + 3 * g + 0];
            float o1 = MW[EN * NHN + 3 * g + 1];
            float o2 = MW[EN * NHN + 3 * g + 2];
            #pragma unroll 4
            for (int e = 0; e < EN; ++e) {
                float x = Ef[row][e];
                o0 += x * MW[e * NHN + 3 * g + 0];
                o1 += x * MW[e * NHN + 3 * g + 1];
                o2 += x * MW[e * NHN + 3 * g + 2];
            }
            float* op = outE + ((size_t)bi * NN + j0 + row) * NHN + 3 * g;
            op[0] = o0; op[1] = o1; op[2] = o2;
        }
    }
}

// ---------------------------------------------------------------------------
// K3a: message mean -> @m_w3 -> node-update hidden layers (fp32, unchanged)
// ---------------------------------------------------------------------------
__global__ __launch_bounds__(256) void k3a(
    const float* __restrict__ pcs, const float* __restrict__ pc,
    const float* __restrict__ m_w3, const float* __restrict__ n_w1,
    const float* __restrict__ n_w2, float* __restrict__ pq)
{
    __shared__ float bufA[32][129];
    __shared__ float bufB[32][129];
    const int t = threadIdx.x;
    const int row0 = blockIdx.x * 32;
    const size_t CH = (size_t)BN * NN * HN;

    #pragma unroll
    for (int it = 0; it < 4; ++it) {
        int idx = t + 256 * it;
        int row = idx >> 5, c4 = idx & 31;
        size_t base = (size_t)(row0 + row) * HN + c4 * 4;
        float4 v0 = *reinterpret_cast<const float4*>(pcs + base);
        float4 v1 = *reinterpret_cast<const float4*>(pcs + CH + base);
        float4 v2 = *reinterpret_cast<const float4*>(pcs + 2 * CH + base);
        float4 v3 = *reinterpret_cast<const float4*>(pcs + 3 * CH + base);
        bufA[row][c4 * 4 + 0] = (v0.x + v1.x + v2.x + v3.x) * (1.f / 128.f);
        bufA[row][c4 * 4 + 1] = (v0.y + v1.y + v2.y + v3.y) * (1.f / 128.f);
        bufA[row][c4 * 4 + 2] = (v0.z + v1.z + v2.z + v3.z) * (1.f / 128.f);
        bufA[row][c4 * 4 + 3] = (v0.w + v1.w + v2.w + v3.w) * (1.f / 128.f);
    }
    __syncthreads();
    const int rg = t & 7, cg = t >> 3;
    const int r0 = rg * 4, c0 = cg * 4;
    {
        float acc[4][4] = {};
        #pragma unroll 4
        for (int k = 0; k < HN; ++k) {
            float4 w = *reinterpret_cast<const float4*>(m_w3 + (size_t)k * HN + c0);
            #pragma unroll
            for (int rr = 0; rr < 4; ++rr) {
                float x = bufA[r0 + rr][k];
                acc[rr][0] += x * w.x; acc[rr][1] += x * w.y;
                acc[rr][2] += x * w.z; acc[rr][3] += x * w.w;
            }
        }
        #pragma unroll
        for (int rr = 0; rr < 4; ++rr)
            #pragma unroll
            for (int cc = 0; cc < 4; ++cc) bufB[r0 + rr][c0 + cc] = acc[rr][cc];
    }
    __syncthreads();
    {
        float acc[4][4] = {};
        #pragma unroll 4
        for (int k = 0; k < HN; ++k) {
            float4 w = *reinterpret_cast<const float4*>(n_w1 + (size_t)k * HN + c0);
            #pragma unroll
            for (int rr = 0; rr < 4; ++rr) {
                float x = bufB[r0 + rr][k];
                acc[rr][0] += x * w.x; acc[rr][1] += x * w.y;
                acc[rr][2] += x * w.z; acc[rr][3] += x * w.w;
            }
        }
        #pragma unroll
        for (int rr = 0; rr < 4; ++rr) {
            float4 cv = *reinterpret_cast<const float4*>(
                pc + (size_t)(row0 + r0 + rr) * HN + c0);
            bufA[r0 + rr][c0 + 0] = frelu(acc[rr][0] + cv.x);
            bufA[r0 + rr][c0 + 1] = frelu(acc[rr][1] + cv.y);
            bufA[r0 + rr][c0 + 2] = frelu(acc[rr][2] + cv.z);
            bufA[r0 + rr][c0 + 3] = frelu(acc[rr][3] + cv.w);
        }
    }
    __syncthreads();
    {
        float acc[4][4] = {};
        #pragma unroll 4
        for (int k = 0; k < HN; ++k) {
            float4 w = *reinterpret_cast<const float4*>(n_w2 + (size_t)k * HN + c0);
            #pragma unroll
            for (int rr = 0; rr < 4; ++rr) {
                float x = bufA[r0 + rr][k];
                acc[rr][0] += x * w.x; acc[rr][1] += x * w.y;
                acc[rr][2] += x * w.z; acc[rr][3] += x * w.w;
            }
        }
        #pragma unroll
        for (int rr = 0; rr < 4; ++rr)
            *reinterpret_cast<float4*>(pq + (size_t)(row0 + r0 + rr) * HN + c0) =
                make_float4(frelu(acc[rr][0]), frelu(acc[rr][1]),
                            frelu(acc[rr][2]), frelu(acc[rr][3]));
    }
}

// ---------------------------------------------------------------------------
// K3b: node_out = node + Q @ n_w3 (fp32, unchanged)
// ---------------------------------------------------------------------------
__global__ __launch_bounds__(256) void k3b(
    const float* __restrict__ pq, const float* __restrict__ n_w3,
    const float* __restrict__ node_src, float* __restrict__ node_dst)
{
    __shared__ float QT[32][129];
    const int t = threadIdx.x;
    const int row0 = blockIdx.x * 32;
    const int cc0 = blockIdx.y * 128;

    #pragma unroll
    for (int it = 0; it < 4; ++it) {
        int idx = t + 256 * it;
        int row = idx >> 5, c4 = idx & 31;
        float4 v = *reinterpret_cast<const float4*>(pq + (size_t)(row0 + row) * HN + c4 * 4);
        QT[row][c4 * 4 + 0] = v.x; QT[row][c4 * 4 + 1] = v.y;
        QT[row][c4 * 4 + 2] = v.z; QT[row][c4 * 4 + 3] = v.w;
    }
    __syncthreads();
    const int rg = t & 7, cg = t >> 3;
    const int r0 = rg * 4, c0 = cg * 4;
    float acc[4][4] = {};
    #pragma unroll 4
    for (int k = 0; k < HN; ++k) {
        float4 w = *reinterpret_cast<const float4*>(n_w3 + (size_t)k * DN + cc0 + c0);
        #pragma unroll
        for (int rr = 0; rr < 4; ++rr) {
            float x = QT[r0 + rr][k];
            acc[rr][0] += x * w.x; acc[rr][1] += x * w.y;
            acc[rr][2] += x * w.z; acc[rr][3] += x * w.w;
        }
    }
    #pragma unroll
    for (int rr = 0; rr < 4; ++rr) {
        size_t off = (size_t)(row0 + r0 + rr) * DN + cc0 + c0;
        float4 nv = *reinterpret_cast<const float4*>(node_src + off);
        *reinterpret_cast<float4*>(node_dst + off) =
            make_float4(nv.x + acc[rr][0], nv.y + acc[rr][1],
                        nv.z + acc[rr][2], nv.w + acc[rr][3]);
    }
}

// ---------------------------------------------------------------------------
extern "C" void kernel_launch(void* const* d_in, const int* in_sizes, int n_in,
                              void* d_out, int out_size, void* d_ws, size_t ws_size,
                              hipStream_t stream)
{
    const float* nodeIn = (const float*)d_in[0];
    const float* edgeIn = (const float*)d_in[1];
    const float* s_w1 = (const float*)d_in[3];
    const float* s_w2 = (const float*)d_in[4];
    const float* m_w1 = (const float*)d_in[5];
    const float* m_w2 = (const float*)d_in[6];
    const float* m_w3 = (const float*)d_in[7];
    const float* n_w1 = (const float*)d_in[8];
    const float* n_w2 = (const float*)d_in[9];
    const float* n_w3 = (const float*)d_in[10];
    const float* e_w1 = (const float*)d_in[11];
    const float* e_w2 = (const float*)d_in[12];
    const float* e_w3 = (const float*)d_in[13];
    const float* maskw = (const float*)d_in[14];
    const float* maskb = (const float*)d_in[15];

    float* outN = (float*)d_out;
    float* outE = outN + (size_t)BN * NN * DN;

    const size_t edgeFl = (size_t)BN * NN * NN * EN;   // 8388608
    const size_t nodeFl = (size_t)BN * NN * DN;        // 786432
    const size_t rowFl  = (size_t)BN * NN * HN;        // 131072
    const size_t wbBytes = 57344 * sizeof(unsigned short);  // 114688, 16B-aligned

    unsigned short* wbp = (unsigned short*)d_ws;
    float* w = (float*)((char*)d_ws + wbBytes);

    const size_t needBig = wbBytes + (edgeFl + nodeFl + 10 * rowFl) * sizeof(float);
    float *edge1, *node1;
    if (ws_size >= needBig) {
        edge1 = w; w += edgeFl;
        node1 = w; w += nodeFl;
    } else {
        // in-place fallback: harness restores inputs before every timed launch
        edge1 = (float*)d_in[1];
        node1 = (float*)d_in[0];
    }
    float* pa  = w; w += rowFl;
    float* pb  = w; w += rowFl;
    float* pc  = w; w += rowFl;
    float* pt  = w; w += rowFl;
    float* psa = w; w += rowFl;
    float* psb = w; w += rowFl;
    float* pcs = w; w += 4 * rowFl;
    float* pq  = pt;   // pt dead after k1b; reuse for Q

    kprep<<<dim3(224), 256, 0, stream>>>(m_w1, e_w1, m_w2, e_w2, e_w3, wbp);

    for (int l = 0; l < 2; ++l) {
        const float* nsrc = l ? (const float*)node1 : nodeIn;
        const float* esrc = l ? (const float*)edge1 : edgeIn;
        float* ndst = l ? outN : node1;

        k1_proj<<<dim3(64, 4), 256, 0, stream>>>(nsrc, m_w1, n_w1, s_w1, pa, pb, pc, pt);
        k1b_shrink<<<dim3(32), 256, 0, stream>>>(pt, s_w2, e_w1, psa, psb);
        if (l == 0)
            k2_mfma<false><<<dim3(4096), 256, 0, stream>>>(
                esrc, pa, pb, psa, psb, wbp, pcs, edge1, maskw, maskb, outE);
        else
            k2_mfma<true><<<dim3(4096), 256, 0, stream>>>(
                esrc, pa, pb, psa, psb, wbp, pcs, nullptr, maskw, maskb, outE);
        k3a<<<dim3(32), 256, 0, stream>>>(pcs, pc, m_w3, n_w1, n_w2, pq);
        k3b<<<dim3(32, 6), 256, 0, stream>>>(pq, n_w3, nsrc, ndst);
    }
}

// Round 4
// 311.068 us; speedup vs baseline: 2.6797x; 1.4262x over previous
//
#include <hip/hip_runtime.h>

#define BN 8
#define NN 128
#define DN 768
#define EN 64
#define MLN 128
#define SN 64
#define HN 128
#define NHN 12

typedef __attribute__((ext_vector_type(8))) short short8;   // 8 bf16 (4 VGPR)
typedef __attribute__((ext_vector_type(4))) float f32x4;    // MFMA C/D

#define MFMA16(a, b, c) __builtin_amdgcn_mfma_f32_16x16x32_bf16(a, b, c, 0, 0, 0)

__device__ __forceinline__ float frelu(float x) { return x > 0.f ? x : 0.f; }

__device__ __forceinline__ unsigned short f2bf(float x) {
    unsigned u = __builtin_bit_cast(unsigned, x);
    u = (u + 0x7fffu + ((u >> 16) & 1u)) >> 16;     // RNE
    return (unsigned short)u;
}

// bf16 weight regions in wb (all [N][K], dst off in shorts):
//  0: w1m   off 0       K=64  N=128   5: wa   off 57344  K=768 N=128
//  1: w1e   off 8192    K=64  N=128   6: wbb  off 155648 K=768 N=128
//  2: w2m   off 16384   K=128 N=128   7: wc   off 253952 K=768 N=128
//  3: w2e   off 32768   K=128 N=128   8: ws1  off 352256 K=768 N=128
//  4: w3e   off 49152   K=128 N=64    9: ws2  off 450560 K=128 N=64
// 10: we1ab off 458752  K=128 N=128  11: wm3  off 475136 K=128 N=128
// 12: wn1m  off 491520  K=128 N=128  13: wn2  off 507904 K=128 N=128
// 14: wn3   off 524288  K=128 N=768       total 622592 shorts
#define WB_TOTAL 622592

// ---------------------------------------------------------------------------
// kprep: LDS-tiled transpose fp32 [K][N] -> bf16 [N][K]. grid (96, 15).
// ---------------------------------------------------------------------------
__global__ __launch_bounds__(256) void kprep(
    const float* __restrict__ m_w1, const float* __restrict__ e_w1,
    const float* __restrict__ m_w2, const float* __restrict__ e_w2,
    const float* __restrict__ e_w3, const float* __restrict__ s_w1,
    const float* __restrict__ s_w2, const float* __restrict__ m_w3,
    const float* __restrict__ n_w1, const float* __restrict__ n_w2,
    const float* __restrict__ n_w3, unsigned short* __restrict__ wb)
{
    __shared__ float TP[32][33];
    const float* src; int K, N; size_t off;
    switch (blockIdx.y) {
        case 0:  src = m_w1 + (size_t)1536 * HN; K = 64;  N = 128; off = 0;      break;
        case 1:  src = e_w1 + (size_t)128 * HN;  K = 64;  N = 128; off = 8192;   break;
        case 2:  src = m_w2;                     K = 128; N = 128; off = 16384;  break;
        case 3:  src = e_w2;                     K = 128; N = 128; off = 32768;  break;
        case 4:  src = e_w3;                     K = 128; N = 64;  off = 49152;  break;
        case 5:  src = m_w1;                     K = 768; N = 128; off = 57344;  break;
        case 6:  src = m_w1 + (size_t)768 * HN;  K = 768; N = 128; off = 155648; break;
        case 7:  src = n_w1 + (size_t)128 * HN;  K = 768; N = 128; off = 253952; break;
        case 8:  src = s_w1;                     K = 768; N = 128; off = 352256; break;
        case 9:  src = s_w2;                     K = 128; N = 64;  off = 450560; break;
        case 10: src = e_w1;                     K = 128; N = 128; off = 458752; break;
        case 11: src = m_w3;                     K = 128; N = 128; off = 475136; break;
        case 12: src = n_w1;                     K = 128; N = 128; off = 491520; break;
        case 13: src = n_w2;                     K = 128; N = 128; off = 507904; break;
        default: src = n_w3;                     K = 128; N = 768; off = 524288; break;
    }
    const int tN = N >> 5;
    const int tx = blockIdx.x;
    const int tn = tx % tN, tk = tx / tN;
    if (tk >= (K >> 5)) return;
    const int k0 = tk * 32, n0 = tn * 32;
    const int t = threadIdx.x, r = t >> 5, c = t & 31;
    #pragma unroll
    for (int p = 0; p < 4; ++p)
        TP[r + 8 * p][c] = src[(size_t)(k0 + r + 8 * p) * N + n0 + c];
    __syncthreads();
    #pragma unroll
    for (int p = 0; p < 4; ++p)
        wb[off + (size_t)(n0 + r + 8 * p) * K + k0 + c] = f2bf(TP[c][r + 8 * p]);
}

// ---------------------------------------------------------------------------
// knode (fused k1+k1b, MFMA): per block 16 node rows, 8 waves.
//   a,b,c = node@{m_w1a,m_w1b,n_w1[128:]}; t = relu(node@s_w1);
//   shrink = t@s_w2; sa|sb = shrink@e_w1[{0:64,64:128}]
// A-frag: lane&15 = row, k = (lane>>4)*8+i.  D: col=lane&15, row=(lane>>4)*4+reg.
// ---------------------------------------------------------------------------
__global__ __launch_bounds__(512) void knode(
    const float* __restrict__ node, const unsigned short* __restrict__ wb,
    float* __restrict__ pa, float* __restrict__ pb, float* __restrict__ pc,
    float* __restrict__ psa, float* __restrict__ psb)
{
    __shared__ unsigned short NT[16][776];
    __shared__ unsigned short TT[16][136];
    __shared__ unsigned short SH[16][72];
    const int t = threadIdx.x;
    const int wid = t >> 6, lane = t & 63;
    const int lrow = lane & 15, ks = lane >> 4;
    const int row0 = blockIdx.x * 16;

    {   // stage 16x768 node rows as bf16
        const int r = t >> 5;
        #pragma unroll
        for (int it = 0; it < 6; ++it) {
            int c4 = ((t & 31) + 32 * it) * 4;
            float4 v = *reinterpret_cast<const float4*>(
                node + (size_t)(row0 + r) * DN + c4);
            ushort4 u;
            u.x = f2bf(v.x); u.y = f2bf(v.y); u.z = f2bf(v.z); u.w = f2bf(v.w);
            *reinterpret_cast<ushort4*>(&NT[r][c4]) = u;
        }
    }
    __syncthreads();

    const f32x4 zf = {0.f, 0.f, 0.f, 0.f};
    const int col = wid * 16 + lrow;

    #pragma unroll
    for (int s = 0; s < 4; ++s) {
        const size_t woff = (s == 0) ? 57344 : (s == 1) ? 155648 :
                            (s == 2) ? 253952 : 352256;
        const unsigned short* W = wb + woff + (size_t)col * 768;
        f32x4 acc = zf;
        #pragma unroll
        for (int kk = 0; kk < 24; ++kk) {
            short8 a = *reinterpret_cast<const short8*>(&NT[lrow][kk * 32 + ks * 8]);
            short8 w = *reinterpret_cast<const short8*>(W + kk * 32 + ks * 8);
            acc = MFMA16(a, w, acc);
        }
        if (s == 0) {
            #pragma unroll
            for (int reg = 0; reg < 4; ++reg)
                pa[(size_t)(row0 + ks * 4 + reg) * HN + col] = acc[reg];
        } else if (s == 1) {
            #pragma unroll
            for (int reg = 0; reg < 4; ++reg)
                pb[(size_t)(row0 + ks * 4 + reg) * HN + col] = acc[reg];
        } else if (s == 2) {
            #pragma unroll
            for (int reg = 0; reg < 4; ++reg)
                pc[(size_t)(row0 + ks * 4 + reg) * HN + col] = acc[reg];
        } else {
            #pragma unroll
            for (int reg = 0; reg < 4; ++reg)
                TT[ks * 4 + reg][col] = f2bf(frelu(acc[reg]));
        }
    }
    __syncthreads();

    if (wid < 4) {   // shrink = TT @ ws2 (K=128, N=64), no relu
        const unsigned short* W = wb + 450560 + (size_t)col * 128;
        f32x4 acc = zf;
        #pragma unroll
        for (int kk = 0; kk < 4; ++kk) {
            short8 a = *reinterpret_cast<const short8*>(&TT[lrow][kk * 32 + ks * 8]);
            short8 w = *reinterpret_cast<const short8*>(W + kk * 32 + ks * 8);
            acc = MFMA16(a, w, acc);
        }
        #pragma unroll
        for (int reg = 0; reg < 4; ++reg)
            SH[ks * 4 + reg][col] = f2bf(acc[reg]);
    }
    __syncthreads();

    {   // sa|sb = SH @ we1ab (K=64 each, [N=128][K=128] with halves at k0/k64)
        const unsigned short* Wa = wb + 458752 + (size_t)col * 128;
        const unsigned short* Wb = Wa + 64;
        f32x4 aa = zf, ab = zf;
        #pragma unroll
        for (int kk = 0; kk < 2; ++kk) {
            short8 a = *reinterpret_cast<const short8*>(&SH[lrow][kk * 32 + ks * 8]);
            aa = MFMA16(a, *reinterpret_cast<const short8*>(Wa + kk * 32 + ks * 8), aa);
            ab = MFMA16(a, *reinterpret_cast<const short8*>(Wb + kk * 32 + ks * 8), ab);
        }
        #pragma unroll
        for (int reg = 0; reg < 4; ++reg) {
            psa[(size_t)(row0 + ks * 4 + reg) * HN + col] = aa[reg];
            psb[(size_t)(row0 + ks * 4 + reg) * HN + col] = ab[reg];
        }
    }
}

// ---------------------------------------------------------------------------
// K2 (MFMA): fused per-edge kernel. Ef dropped from LDS (residual re-reads
// edge from L2); FINAL keeps a fp32 scratch for the mask projection.
// ---------------------------------------------------------------------------
template <bool FINAL>
__global__ __launch_bounds__(256, 6) void k2_mfma(
    const float* __restrict__ edge_src,
    const float* __restrict__ pa, const float* __restrict__ pb,
    const float* __restrict__ psa, const float* __restrict__ psb,
    const unsigned short* __restrict__ wb,
    float* __restrict__ pcs, float* __restrict__ edge_dst,
    const float* __restrict__ maskw, const float* __restrict__ maskb,
    float* __restrict__ outE)
{
    __shared__ unsigned short Eb[32][72];    // bf16 edge tile (A-operand)
    __shared__ unsigned short Ab[32][136];   // H1m, later H2e
    __shared__ unsigned short Bb[32][136];   // H1e
    __shared__ float          ES[FINAL ? 32 : 1][68];
    __shared__ float          MW[EN * NHN + NHN];

    const int t = threadIdx.x;
    const int wid = t >> 6, lane = t & 63;
    const int lrow = lane & 15, ks = lane >> 4;
    const int blk = blockIdx.x;
    const int jc = blk & 3, i = (blk >> 2) & 127, b = blk >> 9;
    const int j0 = jc * 32, bi = b * NN + i;
    const int wn0 = wid * 32;

    const unsigned short* w1m_b = wb;
    const unsigned short* w1e_b = wb + 8192;
    const unsigned short* w2m_b = wb + 16384;
    const unsigned short* w2e_b = wb + 32768;
    const unsigned short* w3e_b = wb + 49152;

    const float* ep = edge_src + ((size_t)bi * NN + j0) * EN;
    {   // stage 32x64 edge tile as bf16
        #pragma unroll
        for (int it = 0; it < 2; ++it) {
            int idx = t + 256 * it;
            int r = idx >> 4, c4 = (idx & 15) * 4;
            float4 v = *reinterpret_cast<const float4*>(ep + r * EN + c4);
            ushort4 u;
            u.x = f2bf(v.x); u.y = f2bf(v.y); u.z = f2bf(v.z); u.w = f2bf(v.w);
            *reinterpret_cast<ushort4*>(&Eb[r][c4]) = u;
        }
    }
    if (FINAL) {
        for (int idx = t; idx < EN * NHN; idx += 256) MW[idx] = maskw[idx];
        if (t < NHN) MW[EN * NHN + t] = maskb[t];
    }
    __syncthreads();

    const f32x4 zf = {0.f, 0.f, 0.f, 0.f};

    // ---- G1m + G1e: E(32x64) @ W1{m,e}(64x128), bias, relu, -> bf16 LDS ----
    {
        f32x4 am[2][2], ae[2][2];
        #pragma unroll
        for (int mt = 0; mt < 2; ++mt)
            #pragma unroll
            for (int nt = 0; nt < 2; ++nt) { am[mt][nt] = zf; ae[mt][nt] = zf; }

        #pragma unroll
        for (int kk = 0; kk < 2; ++kk) {
            short8 a0 = *reinterpret_cast<const short8*>(&Eb[lrow][kk * 32 + ks * 8]);
            short8 a1 = *reinterpret_cast<const short8*>(&Eb[16 + lrow][kk * 32 + ks * 8]);
            #pragma unroll
            for (int nt = 0; nt < 2; ++nt) {
                const int n = wn0 + nt * 16 + lrow;
                short8 bm = *reinterpret_cast<const short8*>(w1m_b + n * 64 + kk * 32 + ks * 8);
                short8 be = *reinterpret_cast<const short8*>(w1e_b + n * 64 + kk * 32 + ks * 8);
                am[0][nt] = MFMA16(a0, bm, am[0][nt]);
                am[1][nt] = MFMA16(a1, bm, am[1][nt]);
                ae[0][nt] = MFMA16(a0, be, ae[0][nt]);
                ae[1][nt] = MFMA16(a1, be, ae[1][nt]);
            }
        }
        #pragma unroll
        for (int nt = 0; nt < 2; ++nt) {
            const int col = wn0 + nt * 16 + lrow;
            const float av  = pa[(size_t)bi * HN + col];
            const float sav = psa[(size_t)bi * HN + col];
            #pragma unroll
            for (int mt = 0; mt < 2; ++mt) {
                #pragma unroll
                for (int reg = 0; reg < 4; ++reg) {
                    const int row = mt * 16 + ks * 4 + reg;
                    const int gj = b * NN + j0 + row;
                    const float bv  = pb[(size_t)gj * HN + col];
                    const float sbv = psb[(size_t)gj * HN + col];
                    Ab[row][col] = f2bf(frelu(am[mt][nt][reg] + av + bv));
                    Bb[row][col] = f2bf(frelu(ae[mt][nt][reg] + sav + sbv));
                }
            }
        }
    }
    __syncthreads();

    // ---- G2m: relu(H1m @ m_w2), fused column sums -> pcs ----
    {
        f32x4 acc[2][2];
        #pragma unroll
        for (int mt = 0; mt < 2; ++mt)
            #pragma unroll
            for (int nt = 0; nt < 2; ++nt) acc[mt][nt] = zf;
        #pragma unroll
        for (int kk = 0; kk < 4; ++kk) {
            short8 a0 = *reinterpret_cast<const short8*>(&Ab[lrow][kk * 32 + ks * 8]);
            short8 a1 = *reinterpret_cast<const short8*>(&Ab[16 + lrow][kk * 32 + ks * 8]);
            #pragma unroll
            for (int nt = 0; nt < 2; ++nt) {
                const int n = wn0 + nt * 16 + lrow;
                short8 bm = *reinterpret_cast<const short8*>(w2m_b + n * 128 + kk * 32 + ks * 8);
                acc[0][nt] = MFMA16(a0, bm, acc[0][nt]);
                acc[1][nt] = MFMA16(a1, bm, acc[1][nt]);
            }
        }
        #pragma unroll
        for (int nt = 0; nt < 2; ++nt) {
            float s = 0.f;
            #pragma unroll
            for (int mt = 0; mt < 2; ++mt)
                #pragma unroll
                for (int reg = 0; reg < 4; ++reg) s += frelu(acc[mt][nt][reg]);
            s += __shfl_xor(s, 16);
            s += __shfl_xor(s, 32);
            if (ks == nt)
                pcs[((size_t)jc * BN * NN + bi) * HN + wn0 + nt * 16 + lrow] = s;
        }
    }

    // ---- G2e: H2e = relu(H1e @ e_w2) (regs until Ab free) ----
    f32x4 h2[2][2];
    {
        #pragma unroll
        for (int mt = 0; mt < 2; ++mt)
            #pragma unroll
            for (int nt = 0; nt < 2; ++nt) h2[mt][nt] = zf;
        #pragma unroll
        for (int kk = 0; kk < 4; ++kk) {
            short8 a0 = *reinterpret_cast<const short8*>(&Bb[lrow][kk * 32 + ks * 8]);
            short8 a1 = *reinterpret_cast<const short8*>(&Bb[16 + lrow][kk * 32 + ks * 8]);
            #pragma unroll
            for (int nt = 0; nt < 2; ++nt) {
                const int n = wn0 + nt * 16 + lrow;
                short8 be = *reinterpret_cast<const short8*>(w2e_b + n * 128 + kk * 32 + ks * 8);
                h2[0][nt] = MFMA16(a0, be, h2[0][nt]);
                h2[1][nt] = MFMA16(a1, be, h2[1][nt]);
            }
        }
    }
    __syncthreads();

    #pragma unroll
    for (int nt = 0; nt < 2; ++nt) {
        const int col = wn0 + nt * 16 + lrow;
        #pragma unroll
        for (int mt = 0; mt < 2; ++mt)
            #pragma unroll
            for (int reg = 0; reg < 4; ++reg)
                Ab[mt * 16 + ks * 4 + reg][col] = f2bf(frelu(h2[mt][nt][reg]));
    }
    __syncthreads();

    // ---- G3e: Eout = H2e @ e_w3 + residual + (edge>0) mask ----
    {
        f32x4 acc3[2]; acc3[0] = zf; acc3[1] = zf;
        const int n0 = wid * 16;
        #pragma unroll
        for (int kk = 0; kk < 4; ++kk) {
            short8 a0 = *reinterpret_cast<const short8*>(&Ab[lrow][kk * 32 + ks * 8]);
            short8 a1 = *reinterpret_cast<const short8*>(&Ab[16 + lrow][kk * 32 + ks * 8]);
            short8 bw = *reinterpret_cast<const short8*>(w3e_b + (n0 + lrow) * 128 + kk * 32 + ks * 8);
            acc3[0] = MFMA16(a0, bw, acc3[0]);
            acc3[1] = MFMA16(a1, bw, acc3[1]);
        }
        const int colc = n0 + lrow;
        #pragma unroll
        for (int mt = 0; mt < 2; ++mt) {
            #pragma unroll
            for (int reg = 0; reg < 4; ++reg) {
                const int row = mt * 16 + ks * 4 + reg;
                const float ev = ep[row * EN + colc];       // L2 re-read (exact fp32)
                const float o = ev + (ev > 0.f ? acc3[mt][reg] : 0.f);
                if (!FINAL)
                    edge_dst[((size_t)bi * NN + j0 + row) * EN + colc] = o;
                else
                    ES[row][colc] = o;
            }
        }
    }

    if (FINAL) {
        __syncthreads();
        if (t < 128) {   // out = EO @ mask_w + mask_b
            int row = t & 31, g = t >> 5;
            float o0 = MW[EN * NHN + 3 * g + 0];
            float o1 = MW[EN * NHN + 3 * g + 1];
            float o2 = MW[EN * NHN + 3 * g + 2];
            #pragma unroll 4
            for (int e = 0; e < EN; ++e) {
                float x = ES[row][e];
                o0 += x * MW[e * NHN + 3 * g + 0];
                o1 += x * MW[e * NHN + 3 * g + 1];
                o2 += x * MW[e * NHN + 3 * g + 2];
            }
            float* op = outE + ((size_t)bi * NN + j0 + row) * NHN + 3 * g;
            op[0] = o0; op[1] = o1; op[2] = o2;
        }
    }
}

// ---------------------------------------------------------------------------
// kupd (fused k3a+k3b, MFMA): per block 16 rows, 8 waves.
//   msg = mean(pcs)/128; M = msg@m_w3; P = relu(M@n_w1[:128] + c);
//   Q = relu(P@n_w2); out = node + Q@n_w3
// ---------------------------------------------------------------------------
__global__ __launch_bounds__(512) void kupd(
    const float* __restrict__ pcs, const float* __restrict__ pc,
    const unsigned short* __restrict__ wb,
    const float* __restrict__ node_src, float* __restrict__ node_dst)
{
    __shared__ unsigned short M1[16][136];
    __shared__ unsigned short M2[16][136];
    const int t = threadIdx.x;
    const int wid = t >> 6, lane = t & 63;
    const int lrow = lane & 15, ks = lane >> 4;
    const int row0 = blockIdx.x * 16;
    const size_t CH = (size_t)BN * NN * HN;
    const f32x4 zf = {0.f, 0.f, 0.f, 0.f};
    const int col = wid * 16 + lrow;

    {   // mean over j-chunks -> bf16 M1
        int r = t >> 5, c4 = (t & 31) * 4;
        size_t base = (size_t)(row0 + r) * HN + c4;
        float4 v0 = *reinterpret_cast<const float4*>(pcs + base);
        float4 v1 = *reinterpret_cast<const float4*>(pcs + CH + base);
        float4 v2 = *reinterpret_cast<const float4*>(pcs + 2 * CH + base);
        float4 v3 = *reinterpret_cast<const float4*>(pcs + 3 * CH + base);
        ushort4 u;
        u.x = f2bf((v0.x + v1.x + v2.x + v3.x) * (1.f / 128.f));
        u.y = f2bf((v0.y + v1.y + v2.y + v3.y) * (1.f / 128.f));
        u.z = f2bf((v0.z + v1.z + v2.z + v3.z) * (1.f / 128.f));
        u.w = f2bf((v0.w + v1.w + v2.w + v3.w) * (1.f / 128.f));
        *reinterpret_cast<ushort4*>(&M1[r][c4]) = u;
    }
    __syncthreads();

    {   // A: M2 = M1 @ m_w3 (no relu)
        const unsigned short* W = wb + 475136 + (size_t)col * 128;
        f32x4 acc = zf;
        #pragma unroll
        for (int kk = 0; kk < 4; ++kk) {
            short8 a = *reinterpret_cast<const short8*>(&M1[lrow][kk * 32 + ks * 8]);
            acc = MFMA16(a, *reinterpret_cast<const short8*>(W + kk * 32 + ks * 8), acc);
        }
        #pragma unroll
        for (int reg = 0; reg < 4; ++reg)
            M2[ks * 4 + reg][col] = f2bf(acc[reg]);
    }
    __syncthreads();

    {   // B: M1 = relu(M2 @ n_w1[:128] + c)
        const unsigned short* W = wb + 491520 + (size_t)col * 128;
        f32x4 acc = zf;
        #pragma unroll
        for (int kk = 0; kk < 4; ++kk) {
            short8 a = *reinterpret_cast<const short8*>(&M2[lrow][kk * 32 + ks * 8]);
            acc = MFMA16(a, *reinterpret_cast<const short8*>(W + kk * 32 + ks * 8), acc);
        }
        #pragma unroll
        for (int reg = 0; reg < 4; ++reg) {
            float cv = pc[(size_t)(row0 + ks * 4 + reg) * HN + col];
            M1[ks * 4 + reg][col] = f2bf(frelu(acc[reg] + cv));
        }
    }
    __syncthreads();

    {   // C: M2 = relu(M1 @ n_w2)
        const unsigned short* W = wb + 507904 + (size_t)col * 128;
        f32x4 acc = zf;
        #pragma unroll
        for (int kk = 0; kk < 4; ++kk) {
            short8 a = *reinterpret_cast<const short8*>(&M1[lrow][kk * 32 + ks * 8]);
            acc = MFMA16(a, *reinterpret_cast<const short8*>(W + kk * 32 + ks * 8), acc);
        }
        #pragma unroll
        for (int reg = 0; reg < 4; ++reg)
            M2[ks * 4 + reg][col] = f2bf(frelu(acc[reg]));
    }
    __syncthreads();

    {   // D: out = node + M2 @ n_w3  (N=768: 8 waves x 6 nt x 16)
        #pragma unroll
        for (int nt = 0; nt < 6; ++nt) {
            const int c768 = wid * 96 + nt * 16 + lrow;
            const unsigned short* W = wb + 524288 + (size_t)c768 * 128;
            f32x4 acc = zf;
            #pragma unroll
            for (int kk = 0; kk < 4; ++kk) {
                short8 a = *reinterpret_cast<const short8*>(&M2[lrow][kk * 32 + ks * 8]);
                acc = MFMA16(a, *reinterpret_cast<const short8*>(W + kk * 32 + ks * 8), acc);
            }
            #pragma unroll
            for (int reg = 0; reg < 4; ++reg) {
                size_t off = (size_t)(row0 + ks * 4 + reg) * DN + c768;
                node_dst[off] = node_src[off] + acc[reg];
            }
        }
    }
}

// ---------------------------------------------------------------------------
extern "C" void kernel_launch(void* const* d_in, const int* in_sizes, int n_in,
                              void* d_out, int out_size, void* d_ws, size_t ws_size,
                              hipStream_t stream)
{
    const float* nodeIn = (const float*)d_in[0];
    const float* edgeIn = (const float*)d_in[1];
    const float* s_w1 = (const float*)d_in[3];
    const float* s_w2 = (const float*)d_in[4];
    const float* m_w1 = (const float*)d_in[5];
    const float* m_w2 = (const float*)d_in[6];
    const float* m_w3 = (const float*)d_in[7];
    const float* n_w1 = (const float*)d_in[8];
    const float* n_w2 = (const float*)d_in[9];
    const float* n_w3 = (const float*)d_in[10];
    const float* e_w1 = (const float*)d_in[11];
    const float* e_w2 = (const float*)d_in[12];
    const float* e_w3 = (const float*)d_in[13];
    const float* maskw = (const float*)d_in[14];
    const float* maskb = (const float*)d_in[15];

    float* outN = (float*)d_out;
    float* outE = outN + (size_t)BN * NN * DN;

    const size_t edgeFl = (size_t)BN * NN * NN * EN;   // 8388608
    const size_t nodeFl = (size_t)BN * NN * DN;        // 786432
    const size_t rowFl  = (size_t)BN * NN * HN;        // 131072
    const size_t wbBytes = (size_t)WB_TOTAL * sizeof(unsigned short);

    unsigned short* wbp = (unsigned short*)d_ws;
    float* w = (float*)((char*)d_ws + wbBytes);

    const size_t needBig = wbBytes + (edgeFl + nodeFl + 9 * rowFl) * sizeof(float);
    float *edge1, *node1;
    if (ws_size >= needBig) {
        edge1 = w; w += edgeFl;
        node1 = w; w += nodeFl;
    } else {
        // in-place fallback: harness restores inputs before every timed launch
        edge1 = (float*)d_in[1];
        node1 = (float*)d_in[0];
    }
    float* pa  = w; w += rowFl;
    float* pb  = w; w += rowFl;
    float* pc  = w; w += rowFl;
    float* psa = w; w += rowFl;
    float* psb = w; w += rowFl;
    float* pcs = w; w += 4 * rowFl;

    kprep<<<dim3(96, 15), 256, 0, stream>>>(m_w1, e_w1, m_w2, e_w2, e_w3,
                                            s_w1, s_w2, m_w3, n_w1, n_w2, n_w3, wbp);

    for (int l = 0; l < 2; ++l) {
        const float* nsrc = l ? (const float*)node1 : nodeIn;
        const float* esrc = l ? (const float*)edge1 : edgeIn;
        float* ndst = l ? outN : node1;

        knode<<<dim3(64), 512, 0, stream>>>(nsrc, wbp, pa, pb, pc, psa, psb);
        if (l == 0)
            k2_mfma<false><<<dim3(4096), 256, 0, stream>>>(
                esrc, pa, pb, psa, psb, wbp, pcs, edge1, maskw, maskb, outE);
        else
            k2_mfma<true><<<dim3(4096), 256, 0, stream>>>(
                esrc, pa, pb, psa, psb, wbp, pcs, nullptr, maskw, maskb, outE);
        kupd<<<dim3(64), 512, 0, stream>>>(pcs, pc, wbp, nsrc, ndst);
    }
}